// Round 1
// baseline (2403.158 us; speedup 1.0000x reference)
//
#include <hip/hip_runtime.h>
#include <hip/hip_bf16.h>

// B=128, T=512, F_IN=128, H=128
#define EPS_ 1e-5f

typedef __attribute__((ext_vector_type(4))) float f32x4;
typedef __attribute__((ext_vector_type(8))) short s16x8;
typedef __attribute__((ext_vector_type(4))) short s16x4;
typedef unsigned short u16;

static __device__ __forceinline__ u16 f2bf(float f) {
  __hip_bfloat16 h = __float2bfloat16(f);
  return *reinterpret_cast<u16*>(&h);
}
static __device__ __forceinline__ float bf2f(u16 u) {
  union { float f; unsigned int i; } v; v.i = ((unsigned int)u) << 16; return v.f;
}
static __device__ __forceinline__ float sigf(float x) {
  return __builtin_amdgcn_rcpf(1.f + __expf(-x));
}
static __device__ __forceinline__ float tanhf_(float x) {
  return 2.f * __builtin_amdgcn_rcpf(1.f + __expf(-2.f * x)) - 1.f;
}
static __device__ __forceinline__ f32x4 mfma16(s16x8 a, s16x8 b, f32x4 c) {
  return __builtin_amdgcn_mfma_f32_16x16x32_bf16(a, b, c, 0, 0, 0);
}

// ---------------- weight pre-permute: (d,4H,K) f32 -> frag layout bf16 -------
// dst linear: ((((d*NKS+ks)*4+g)*8+w)*64+lane)*8+e ; r=g*128+w*16+(lane&15),
// k=ks*32+(lane>>4)*8+e  (A-frag mapping of mfma_f32_16x16x32_bf16)
__global__ void convw_kernel(const float* __restrict__ src, u16* __restrict__ dst,
                             int KIN, int ksbits, int total) {
  int i = blockIdx.x * 256 + threadIdx.x;
  if (i >= total) return;
  int e = i & 7;
  int lane = (i >> 3) & 63;
  int w = (i >> 9) & 7;
  int g = (i >> 12) & 3;
  int t2 = i >> 14;
  int ks = t2 & ((1 << ksbits) - 1);
  int d = t2 >> ksbits;
  int r = g * 128 + w * 16 + (lane & 15);
  int k = ks * 32 + (lane >> 4) * 8 + e;
  dst[i] = f2bf(src[((size_t)d * 512 + r) * KIN + k]);
}

// conv weight transpose (O,I,3) -> [tap][i][oc]
__global__ void transw_kernel(const float* __restrict__ src, float* __restrict__ dst,
                              int IC, int OC, int total) {
  int n = blockIdx.x * 256 + threadIdx.x;
  if (n >= total) return;
  int oc = n % OC;
  int r = n / OC;
  int i = r % IC;
  int tap = r / IC;
  dst[n] = src[(oc * IC + i) * 3 + tap];
}

// ---------------- conv1d (k=3,pad=1) channels-last + batch-stat atomics ------
// xin (B,T,IC) [conv2 applies input BN+ReLU from stats_in], wt [tap][i][oc],
// yout (B,T,OC) raw (with conv bias), stats_out[oc*2]={sum,sumsq}
template<int IC, int OC, bool HASBN>
__global__ __launch_bounds__(256) void conv_kernel(
    const float* __restrict__ xin, const float* __restrict__ wt,
    const float* __restrict__ bsrc, const float* __restrict__ stats_in,
    const float* __restrict__ g_in, const float* __restrict__ beta_in,
    float* __restrict__ yout, float* __restrict__ stats_out) {
  constexpr int OCPT = OC / 4;
  __shared__ float xlds[66][IC + 1];   // +1 pad: inner-loop reads conflict-free
  __shared__ float insc[IC], insh[IC];

  const int tid = threadIdx.x;
  const int b = blockIdx.x >> 3;
  const int t0 = (blockIdx.x & 7) * 64;

  if constexpr (HASBN) {
    for (int c = tid; c < IC; c += 256) {
      float s0 = stats_in[2 * c], s1 = stats_in[2 * c + 1];
      float m = s0 * (1.f / 65536.f);
      float v = s1 * (1.f / 65536.f) - m * m;
      float inv = rsqrtf(v + EPS_);
      float a = g_in[c] * inv;
      insc[c] = a; insh[c] = beta_in[c] - m * a;
    }
    __syncthreads();
  }

  for (int n = tid; n < 66 * (IC / 4); n += 256) {
    int row = n / (IC / 4);
    int c4 = (n % (IC / 4)) * 4;
    int t = t0 + row - 1;
    float v0 = 0.f, v1 = 0.f, v2 = 0.f, v3 = 0.f;
    if (t >= 0 && t < 512) {
      f32x4 v = *(const f32x4*)&xin[((size_t)b * 512 + t) * IC + c4];
      v0 = v[0]; v1 = v[1]; v2 = v[2]; v3 = v[3];
      if constexpr (HASBN) {  // pad rows stay 0 (zero AFTER bn+relu semantics)
        v0 = fmaxf(v0 * insc[c4 + 0] + insh[c4 + 0], 0.f);
        v1 = fmaxf(v1 * insc[c4 + 1] + insh[c4 + 1], 0.f);
        v2 = fmaxf(v2 * insc[c4 + 2] + insh[c4 + 2], 0.f);
        v3 = fmaxf(v3 * insc[c4 + 3] + insh[c4 + 3], 0.f);
      }
    }
    xlds[row][c4 + 0] = v0; xlds[row][c4 + 1] = v1;
    xlds[row][c4 + 2] = v2; xlds[row][c4 + 3] = v3;
  }
  __syncthreads();

  const int tt = tid & 63;              // one t per thread
  const int ocb = (tid >> 6) * OCPT;    // wave-uniform oc base -> broadcast w loads
  float acc[OCPT];
#pragma unroll
  for (int j = 0; j < OCPT; ++j) acc[j] = 0.f;

#pragma unroll
  for (int tap = 0; tap < 3; ++tap) {
    const float* xr = &xlds[tt + tap][0];
    const float* wr0 = &wt[(size_t)tap * IC * OC + ocb];
#pragma unroll 4
    for (int i = 0; i < IC; ++i) {
      float xv = xr[i];
      const float* wr = wr0 + i * OC;
#pragma unroll
      for (int j4 = 0; j4 < OCPT; j4 += 4) {
        f32x4 wv = *(const f32x4*)&wr[j4];
        acc[j4 + 0] = fmaf(xv, wv[0], acc[j4 + 0]);
        acc[j4 + 1] = fmaf(xv, wv[1], acc[j4 + 1]);
        acc[j4 + 2] = fmaf(xv, wv[2], acc[j4 + 2]);
        acc[j4 + 3] = fmaf(xv, wv[3], acc[j4 + 3]);
      }
    }
  }

  const int t = t0 + tt;
#pragma unroll
  for (int j = 0; j < OCPT; ++j) acc[j] += bsrc[ocb + j];
  float* yr = &yout[((size_t)b * 512 + t) * OC + ocb];
#pragma unroll
  for (int j4 = 0; j4 < OCPT; j4 += 4) {
    f32x4 o; o[0] = acc[j4]; o[1] = acc[j4 + 1]; o[2] = acc[j4 + 2]; o[3] = acc[j4 + 3];
    *(f32x4*)&yr[j4] = o;
  }

  // batch stats: wave-reduce over the 64 t's, one atomic pair per (block, oc)
#pragma unroll
  for (int j = 0; j < OCPT; ++j) {
    float s = acc[j];
    float qv = s * s;
#pragma unroll
    for (int m = 32; m > 0; m >>= 1) {
      s += __shfl_xor(s, m, 64);
      qv += __shfl_xor(qv, m, 64);
    }
    if ((tid & 63) == 0) {
      atomicAdd(&stats_out[2 * (ocb + j)], s);
      atomicAdd(&stats_out[2 * (ocb + j) + 1], qv);
    }
  }
}

// ---------------- fused bi-LSTM layer (one direction+16 samples per block) ---
// 512 thr = 8 waves; wave w owns h-units [w*16,w*16+16) for ALL 4 gates
// gates(512x16) = wih·x[t] (streamed frags) + whh·h[t-1] (resident frags) + b
// D-frag: col(sample)=lane&15, row=(lane>>4)*4+e  -> c,h update fully in-lane
template<int KIN, bool BN>
__global__ __launch_bounds__(512, 1) void lstm_kernel(
    const void* __restrict__ inx_, const float* __restrict__ stats,
    const float* __restrict__ bng, const float* __restrict__ bnb,
    const u16* __restrict__ wihP, const u16* __restrict__ whhP,
    const float* __restrict__ bias, u16* __restrict__ hout) {
  constexpr int NKS = KIN / 32;
  constexpr int XSTR = KIN + 8;      // pad -> <=2-way bank aliasing (free)
  __shared__ u16 hl[16][136];        // h[sample][unit] bf16, padded
  __shared__ u16 xl[2][16][XSTR];    // staged input, double buffered
  __shared__ float sc[128], sh[128];

  const int tid = threadIdx.x;
  const int wv = tid >> 6;
  const int lane = tid & 63;
  const int q = lane >> 4;
  const int col = lane & 15;
  const int dir = blockIdx.x >> 3;
  const int b0 = (blockIdx.x & 7) * 16;

  if constexpr (BN) {
    for (int c = tid; c < 128; c += 512) {
      float s0 = stats[2 * c], s1 = stats[2 * c + 1];
      float m = s0 * (1.f / 65536.f);
      float v = s1 * (1.f / 65536.f) - m * m;
      float inv = rsqrtf(v + EPS_);
      float a = bng[c] * inv;
      sc[c] = a; sh[c] = bnb[c] - m * a;
    }
  }
  for (int n = tid; n < 16 * 136; n += 512) (&hl[0][0])[n] = 0;

  const s16x8* whhv = (const s16x8*)whhP;
  const s16x8* wihv = (const s16x8*)wihP;
  s16x8 awhh[4][4];   // resident recurrent weights: [ks][gate]
#pragma unroll
  for (int ks = 0; ks < 4; ++ks)
#pragma unroll
    for (int g = 0; g < 4; ++g)
      awhh[ks][g] = whhv[(((dir * 4 + ks) * 4 + g) * 8 + wv) * 64 + lane];

  f32x4 bias4[4];
#pragma unroll
  for (int g = 0; g < 4; ++g)
    bias4[g] = *(const f32x4*)&bias[dir * 512 + g * 128 + wv * 16 + q * 4];

  const int ss = tid >> 5;   // staging: sample
  const int cc = tid & 31;   // staging: chunk
  const float* xf = (const float*)inx_;
  const u16* xh = (const u16*)inx_;

  __syncthreads();   // sc/sh + hl zeros visible

  {  // prologue: stage x[t_first] into buffer 0
    int t0i = dir ? 511 : 0;
    if constexpr (KIN == 128) {
      f32x4 v = *(const f32x4*)&xf[((size_t)(b0 + ss) * 512 + t0i) * 128 + cc * 4];
      s16x4 u;
#pragma unroll
      for (int j = 0; j < 4; ++j) {
        float xx = v[j];
        if constexpr (BN) xx = fmaxf(xx * sc[cc * 4 + j] + sh[cc * 4 + j], 0.f);
        u[j] = (short)f2bf(xx);
      }
      *(s16x4*)&xl[0][ss][cc * 4] = u;
    } else {
      s16x8 v = *(const s16x8*)&xh[((size_t)(b0 + ss) * 512 + t0i) * 256 + cc * 8];
      *(s16x8*)&xl[0][ss][cc * 8] = v;
    }
  }
  __syncthreads();

  float c0 = 0.f, c1 = 0.f, c2 = 0.f, c3 = 0.f;
  int cur = 0;

  for (int it = 0; it < 512; ++it) {
    const int t = dir ? (511 - it) : it;
    const int itn = (it < 511) ? (it + 1) : 511;
    const int tn = dir ? (511 - itn) : itn;

    // issue next-x global loads early (consumed after 2nd barrier)
    f32x4 xnf; s16x8 xnh;
    if constexpr (KIN == 128)
      xnf = *(const f32x4*)&xf[((size_t)(b0 + ss) * 512 + tn) * 128 + cc * 4];
    else
      xnh = *(const s16x8*)&xh[((size_t)(b0 + ss) * 512 + tn) * 256 + cc * 8];

    // stream wih frags (L2-hot; latency hidden under ds_reads + whh MFMAs)
    s16x8 aw[NKS][4];
#pragma unroll
    for (int ks = 0; ks < NKS; ++ks)
#pragma unroll
      for (int g = 0; g < 4; ++g)
        aw[ks][g] = wihv[(((dir * NKS + ks) * 4 + g) * 8 + wv) * 64 + lane];

    // B-frags from LDS
    s16x8 bh[4], bx[NKS];
#pragma unroll
    for (int ks = 0; ks < 4; ++ks) bh[ks] = *(const s16x8*)&hl[col][ks * 32 + q * 8];
#pragma unroll
    for (int ks = 0; ks < NKS; ++ks) bx[ks] = *(const s16x8*)&xl[cur][col][ks * 32 + q * 8];

    f32x4 a0 = bias4[0], a1 = bias4[1], a2 = bias4[2], a3 = bias4[3];
#pragma unroll
    for (int ks = 0; ks < 4; ++ks) {
      a0 = mfma16(awhh[ks][0], bh[ks], a0);
      a1 = mfma16(awhh[ks][1], bh[ks], a1);
      a2 = mfma16(awhh[ks][2], bh[ks], a2);
      a3 = mfma16(awhh[ks][3], bh[ks], a3);
    }
#pragma unroll
    for (int ks = 0; ks < NKS; ++ks) {
      a0 = mfma16(aw[ks][0], bx[ks], a0);
      a1 = mfma16(aw[ks][1], bx[ks], a1);
      a2 = mfma16(aw[ks][2], bx[ks], a2);
      a3 = mfma16(aw[ks][3], bx[ks], a3);
    }

    // elementwise gate math (i,f,g,o) for 4 (sample,unit) slots per lane
    f32x4 hn;
    {
      float cp0 = c0, cp1 = c1, cp2 = c2, cp3 = c3;
#define GATE_STEP(E, CP)                                            \
      {                                                             \
        float iv = a0[E], fv = a1[E], gv = a2[E], ov = a3[E];       \
        float cn = sigf(fv) * CP + sigf(iv) * tanhf_(gv);           \
        CP = cn;                                                    \
        hn[E] = sigf(ov) * tanhf_(cn);                              \
      }
      GATE_STEP(0, cp0) GATE_STEP(1, cp1) GATE_STEP(2, cp2) GATE_STEP(3, cp3)
#undef GATE_STEP
      c0 = cp0; c1 = cp1; c2 = cp2; c3 = cp3;
    }

    s16x4 hb;
#pragma unroll
    for (int e = 0; e < 4; ++e) hb[e] = (short)f2bf(hn[e]);
    *(s16x4*)&hout[((size_t)(b0 + col) * 512 + t) * 256 + dir * 128 + wv * 16 + q * 4] = hb;

    __syncthreads();   // all hl/xl[cur] reads done
    *(s16x4*)&hl[col][wv * 16 + q * 4] = hb;
    if constexpr (KIN == 128) {
      s16x4 u;
#pragma unroll
      for (int j = 0; j < 4; ++j) {
        float xx = xnf[j];
        if constexpr (BN) xx = fmaxf(xx * sc[cc * 4 + j] + sh[cc * 4 + j], 0.f);
        u[j] = (short)f2bf(xx);
      }
      *(s16x4*)&xl[cur ^ 1][ss][cc * 4] = u;
    } else {
      *(s16x8*)&xl[cur ^ 1][ss][cc * 8] = xnh;
    }
    __syncthreads();   // writes visible for next step
    cur ^= 1;
  }
}

// ---------------- attention pooling: scores -> softmax -> attended -----------
__global__ __launch_bounds__(256) void attn_kernel(
    const u16* __restrict__ h1, const float* __restrict__ attw,
    const float* __restrict__ attb, float* __restrict__ out_attn,
    float* __restrict__ attended) {
  const int b = blockIdx.x;
  const int tid = threadIdx.x;
  __shared__ float wl[256];
  __shared__ float sl[512];
  __shared__ float red[256];

  wl[tid] = attw[tid];
  __syncthreads();

#pragma unroll
  for (int rep = 0; rep < 2; ++rep) {
    int tt = tid + rep * 256;
    const u16* hr = &h1[((size_t)b * 512 + tt) * 256];
    float s = 0.f;
    for (int d = 0; d < 256; d += 8) {
      s16x8 v = *(const s16x8*)&hr[d];
#pragma unroll
      for (int j = 0; j < 8; ++j) s += bf2f((u16)v[j]) * wl[d + j];
    }
    sl[tt] = s + attb[0];
  }
  __syncthreads();

  red[tid] = fmaxf(sl[tid], sl[tid + 256]);
  __syncthreads();
  for (int st = 128; st > 0; st >>= 1) {
    if (tid < st) red[tid] = fmaxf(red[tid], red[tid + st]);
    __syncthreads();
  }
  const float mx = red[0];
  __syncthreads();

  float e0 = __expf(sl[tid] - mx);
  float e1 = __expf(sl[tid + 256] - mx);
  sl[tid] = e0; sl[tid + 256] = e1;
  red[tid] = e0 + e1;
  __syncthreads();
  for (int st = 128; st > 0; st >>= 1) {
    if (tid < st) red[tid] += red[tid + st];
    __syncthreads();
  }
  const float inv = 1.f / red[0];

  out_attn[(size_t)b * 512 + tid] = sl[tid] * inv;
  out_attn[(size_t)b * 512 + tid + 256] = sl[tid + 256] * inv;
  __syncthreads();

  if (tid < 128) {   // thread per d-pair
    float a0 = 0.f, a1 = 0.f;
    for (int t = 0; t < 512; ++t) {
      float p = sl[t] * inv;
      unsigned int vv = *(const unsigned int*)&h1[((size_t)b * 512 + t) * 256 + tid * 2];
      a0 += p * bf2f((u16)(vv & 0xffff));
      a1 += p * bf2f((u16)(vv >> 16));
    }
    attended[b * 256 + tid * 2] = a0;
    attended[b * 256 + tid * 2 + 1] = a1;
  }
}

// ---------------- group-routed decoder MLP (selected expert only) ------------
__global__ __launch_bounds__(64) void dec_kernel(
    const float* __restrict__ attended, const int* __restrict__ labels,
    const float* __restrict__ w1, const float* __restrict__ b1,
    const float* __restrict__ w2, const float* __restrict__ b2,
    const float* __restrict__ w3, const float* __restrict__ b3,
    float* __restrict__ preds) {
  const int b = blockIdx.x;
  const int tid = threadIdx.x;
  const int g = labels[b];
  __shared__ float al[256];
  __shared__ float hl1[64];
  __shared__ float hl2[32];

  for (int i = tid; i < 256; i += 64) al[i] = attended[b * 256 + i];
  __syncthreads();

  {
    const float* wr = &w1[(size_t)(g * 64 + tid) * 256];
    float a = b1[g * 64 + tid];
    for (int d = 0; d < 256; d += 4) {
      f32x4 wv = *(const f32x4*)&wr[d];
      a += al[d] * wv[0] + al[d + 1] * wv[1] + al[d + 2] * wv[2] + al[d + 3] * wv[3];
    }
    hl1[tid] = fmaxf(a, 0.f);
  }
  __syncthreads();
  if (tid < 32) {
    const float* wr = &w2[(size_t)(g * 32 + tid) * 64];
    float a = b2[g * 32 + tid];
    for (int d = 0; d < 64; d += 4) {
      f32x4 wv = *(const f32x4*)&wr[d];
      a += hl1[d] * wv[0] + hl1[d + 1] * wv[1] + hl1[d + 2] * wv[2] + hl1[d + 3] * wv[3];
    }
    hl2[tid] = fmaxf(a, 0.f);
  }
  __syncthreads();
  if (tid < 32) {
    float a = hl2[tid] * w3[g * 32 + tid];
#pragma unroll
    for (int m = 16; m > 0; m >>= 1) a += __shfl_xor(a, m, 32);
    if (tid == 0) preds[b] = a + b3[g];
  }
}

// ---------------- host-side pipeline ----------------------------------------
extern "C" void kernel_launch(void* const* d_in, const int* in_sizes, int n_in,
                              void* d_out, int out_size, void* d_ws, size_t ws_size,
                              hipStream_t stream) {
  const float* x      = (const float*)d_in[0];
  const int*   labels = (const int*)d_in[1];
  const float* conv1w = (const float*)d_in[2];
  const float* conv1b = (const float*)d_in[3];
  const float* bn1g   = (const float*)d_in[4];
  const float* bn1b   = (const float*)d_in[5];
  const float* conv2w = (const float*)d_in[6];
  const float* conv2b = (const float*)d_in[7];
  const float* bn2g   = (const float*)d_in[8];
  const float* bn2b   = (const float*)d_in[9];
  const float* wih0   = (const float*)d_in[10];
  const float* whh0   = (const float*)d_in[11];
  const float* b0     = (const float*)d_in[12];
  const float* wih1   = (const float*)d_in[13];
  const float* whh1   = (const float*)d_in[14];
  const float* b1     = (const float*)d_in[15];
  const float* attw   = (const float*)d_in[16];
  const float* attb   = (const float*)d_in[17];
  const float* dw1    = (const float*)d_in[18];
  const float* db1    = (const float*)d_in[19];
  const float* dw2    = (const float*)d_in[20];
  const float* db2    = (const float*)d_in[21];
  const float* dw3    = (const float*)d_in[22];
  const float* db3    = (const float*)d_in[23];

  char* ws = (char*)d_ws;
  u16*   wih0P = (u16*)  (ws + 0x000000);  // 256KB  bf16 frag layout
  u16*   whh0P = (u16*)  (ws + 0x040000);  // 256KB
  u16*   wih1P = (u16*)  (ws + 0x080000);  // 512KB
  u16*   whh1P = (u16*)  (ws + 0x100000);  // 256KB
  float* wt1   = (float*)(ws + 0x140000);  // 96KB   conv1 w transposed
  float* wt2   = (float*)(ws + 0x158000);  // 96KB
  float* st1   = (float*)(ws + 0x170000);  // 512B   {sum,sumsq} x64
  float* st2   = (float*)(ws + 0x170200);  // 1KB    x128
  float* attd  = (float*)(ws + 0x170600);  // 128KB  attended (B,256)
  float* y1    = (float*)(ws + 0x200000);  // 16MB   conv1 raw (B,T,64)
  float* y2    = (float*)(ws + 0x1200000); // 32MB   conv2 raw (B,T,128)
  u16*   h0    = (u16*)  (ws + 0x3200000); // 32MB   bf16 (B,T,256)
  u16*   h1    = (u16*)  (ws + 0x200000);  // 32MB   overlays dead y1/y2

  float* preds    = (float*)d_out;         // (B,1)
  float* attn_out = (float*)d_out + 128;   // (B,T)

  hipMemsetAsync(ws + 0x170000, 0, 0x600, stream);  // zero stats (re-poisoned ws)

  convw_kernel<<<512, 256, 0, stream>>>(wih0, wih0P, 128, 2, 131072);
  convw_kernel<<<512, 256, 0, stream>>>(whh0, whh0P, 128, 2, 131072);
  convw_kernel<<<1024, 256, 0, stream>>>(wih1, wih1P, 256, 3, 262144);
  convw_kernel<<<512, 256, 0, stream>>>(whh1, whh1P, 128, 2, 131072);
  transw_kernel<<<96, 256, 0, stream>>>(conv1w, wt1, 128, 64, 24576);
  transw_kernel<<<96, 256, 0, stream>>>(conv2w, wt2, 64, 128, 24576);

  conv_kernel<128, 64, false><<<1024, 256, 0, stream>>>(
      x, wt1, conv1b, nullptr, nullptr, nullptr, y1, st1);
  conv_kernel<64, 128, true><<<1024, 256, 0, stream>>>(
      y1, wt2, conv2b, st1, bn1g, bn1b, y2, st2);

  lstm_kernel<128, true><<<16, 512, 0, stream>>>(
      y2, st2, bn2g, bn2b, wih0P, whh0P, b0, h0);
  lstm_kernel<256, false><<<16, 512, 0, stream>>>(
      h0, nullptr, nullptr, nullptr, wih1P, whh1P, b1, h1);

  attn_kernel<<<128, 256, 0, stream>>>(h1, attw, attb, attn_out, attd);
  dec_kernel<<<128, 64, 0, stream>>>(attd, labels, dw1, db1, dw2, db2, dw3, db3, preds);
}

// Round 3
// 2120.954 us; speedup vs baseline: 1.1331x; 1.1331x over previous
//
#include <hip/hip_runtime.h>
#include <hip/hip_bf16.h>

// B=128, T=512, F_IN=128, H=128
#define EPS_ 1e-5f

typedef __attribute__((ext_vector_type(4))) float f32x4;
typedef __attribute__((ext_vector_type(8))) short s16x8;
typedef __attribute__((ext_vector_type(4))) short s16x4;
typedef unsigned short u16;

static __device__ __forceinline__ u16 f2bf(float f) {
  __hip_bfloat16 h = __float2bfloat16(f);
  return *reinterpret_cast<u16*>(&h);
}
static __device__ __forceinline__ float bf2f(u16 u) {
  union { float f; unsigned int i; } v; v.i = ((unsigned int)u) << 16; return v.f;
}
static __device__ __forceinline__ float sigf(float x) {
  return __builtin_amdgcn_rcpf(1.f + __expf(-x));
}
static __device__ __forceinline__ float tanhf_(float x) {
  return 2.f * __builtin_amdgcn_rcpf(1.f + __expf(-2.f * x)) - 1.f;
}
static __device__ __forceinline__ f32x4 mfma16(s16x8 a, s16x8 b, f32x4 c) {
  return __builtin_amdgcn_mfma_f32_16x16x32_bf16(a, b, c, 0, 0, 0);
}

// ---------------- weight pre-permute: (d,4H,K) f32 -> A-frag layout bf16 -----
// dst linear: ((((d*NKS+ks)*4+g)*8+w)*64+lane)*8+e ; r=g*128+w*16+(lane&15),
// k=ks*32+(lane>>4)*8+e  (A-frag mapping of mfma_f32_16x16x32_bf16)
__global__ void convw_kernel(const float* __restrict__ src, u16* __restrict__ dst,
                             int KIN, int ksbits, int total) {
  int i = blockIdx.x * 256 + threadIdx.x;
  if (i >= total) return;
  int e = i & 7;
  int lane = (i >> 3) & 63;
  int w = (i >> 9) & 7;
  int g = (i >> 12) & 3;
  int t2 = i >> 14;
  int ks = t2 & ((1 << ksbits) - 1);
  int d = t2 >> ksbits;
  int r = g * 128 + w * 16 + (lane & 15);
  int k = ks * 32 + (lane >> 4) * 8 + e;
  dst[i] = f2bf(src[((size_t)d * 512 + r) * KIN + k]);
}

// conv weight transpose (O,I,3) -> [tap][i][oc]
__global__ void transw_kernel(const float* __restrict__ src, float* __restrict__ dst,
                              int IC, int OC, int total) {
  int n = blockIdx.x * 256 + threadIdx.x;
  if (n >= total) return;
  int oc = n % OC;
  int r = n / OC;
  int i = r % IC;
  int tap = r / IC;
  dst[n] = src[(oc * IC + i) * 3 + tap];
}

// ---------------- conv1d (k=3,pad=1) channels-last + batch-stat atomics ------
template<int IC, int OC, bool HASBN>
__global__ __launch_bounds__(256) void conv_kernel(
    const float* __restrict__ xin, const float* __restrict__ wt,
    const float* __restrict__ bsrc, const float* __restrict__ stats_in,
    const float* __restrict__ g_in, const float* __restrict__ beta_in,
    float* __restrict__ yout, float* __restrict__ stats_out) {
  constexpr int OCPT = OC / 4;
  __shared__ float xlds[66][IC + 1];
  __shared__ float insc[IC], insh[IC];

  const int tid = threadIdx.x;
  const int b = blockIdx.x >> 3;
  const int t0 = (blockIdx.x & 7) * 64;

  if constexpr (HASBN) {
    for (int c = tid; c < IC; c += 256) {
      float s0 = stats_in[2 * c], s1 = stats_in[2 * c + 1];
      float m = s0 * (1.f / 65536.f);
      float v = s1 * (1.f / 65536.f) - m * m;
      float inv = rsqrtf(v + EPS_);
      float a = g_in[c] * inv;
      insc[c] = a; insh[c] = beta_in[c] - m * a;
    }
    __syncthreads();
  }

  for (int n = tid; n < 66 * (IC / 4); n += 256) {
    int row = n / (IC / 4);
    int c4 = (n % (IC / 4)) * 4;
    int t = t0 + row - 1;
    float v0 = 0.f, v1 = 0.f, v2 = 0.f, v3 = 0.f;
    if (t >= 0 && t < 512) {
      f32x4 v = *(const f32x4*)&xin[((size_t)b * 512 + t) * IC + c4];
      v0 = v[0]; v1 = v[1]; v2 = v[2]; v3 = v[3];
      if constexpr (HASBN) {
        v0 = fmaxf(v0 * insc[c4 + 0] + insh[c4 + 0], 0.f);
        v1 = fmaxf(v1 * insc[c4 + 1] + insh[c4 + 1], 0.f);
        v2 = fmaxf(v2 * insc[c4 + 2] + insh[c4 + 2], 0.f);
        v3 = fmaxf(v3 * insc[c4 + 3] + insh[c4 + 3], 0.f);
      }
    }
    xlds[row][c4 + 0] = v0; xlds[row][c4 + 1] = v1;
    xlds[row][c4 + 2] = v2; xlds[row][c4 + 3] = v3;
  }
  __syncthreads();

  const int tt = tid & 63;
  const int ocb = (tid >> 6) * OCPT;
  float acc[OCPT];
#pragma unroll
  for (int j = 0; j < OCPT; ++j) acc[j] = 0.f;

#pragma unroll
  for (int tap = 0; tap < 3; ++tap) {
    const float* xr = &xlds[tt + tap][0];
    const float* wr0 = &wt[(size_t)tap * IC * OC + ocb];
#pragma unroll 4
    for (int i = 0; i < IC; ++i) {
      float xv = xr[i];
      const float* wr = wr0 + i * OC;
#pragma unroll
      for (int j4 = 0; j4 < OCPT; j4 += 4) {
        f32x4 wv = *(const f32x4*)&wr[j4];
        acc[j4 + 0] = fmaf(xv, wv[0], acc[j4 + 0]);
        acc[j4 + 1] = fmaf(xv, wv[1], acc[j4 + 1]);
        acc[j4 + 2] = fmaf(xv, wv[2], acc[j4 + 2]);
        acc[j4 + 3] = fmaf(xv, wv[3], acc[j4 + 3]);
      }
    }
  }

  const int t = t0 + tt;
#pragma unroll
  for (int j = 0; j < OCPT; ++j) acc[j] += bsrc[ocb + j];
  float* yr = &yout[((size_t)b * 512 + t) * OC + ocb];
#pragma unroll
  for (int j4 = 0; j4 < OCPT; j4 += 4) {
    f32x4 o; o[0] = acc[j4]; o[1] = acc[j4 + 1]; o[2] = acc[j4 + 2]; o[3] = acc[j4 + 3];
    *(f32x4*)&yr[j4] = o;
  }

#pragma unroll
  for (int j = 0; j < OCPT; ++j) {
    float s = acc[j];
    float qv = s * s;
#pragma unroll
    for (int m = 32; m > 0; m >>= 1) {
      s += __shfl_xor(s, m, 64);
      qv += __shfl_xor(qv, m, 64);
    }
    if ((tid & 63) == 0) {
      atomicAdd(&stats_out[2 * (ocb + j)], s);
      atomicAdd(&stats_out[2 * (ocb + j) + 1], qv);
    }
  }
}

// ---------------- xg = wih·x + b, batched over all (dir,b,t) -----------------
// Output layout = LSTM D-frag order: elem((((dir*8+bg)*512+t)*8+wv)*4+g)*256
// + lane*4 + e, bf16. 256 blocks of 512 thr; aw resident per wave.
template<int KIN, bool BN>
__global__ __launch_bounds__(512, 1) void xg_kernel(
    const void* __restrict__ xin_, const float* __restrict__ stats,
    const float* __restrict__ bng, const float* __restrict__ bnb,
    const u16* __restrict__ wihP, const float* __restrict__ bias,
    u16* __restrict__ xgo) {
  constexpr int NKS = KIN / 32;
  constexpr int XSTR = KIN + 8;
  __shared__ u16 xl[2][16][XSTR];
  __shared__ float sc[128], sh[128];

  const int tid = threadIdx.x;
  const int wv = tid >> 6, lane = tid & 63, q = lane >> 4, col = lane & 15;
  const int bid = blockIdx.x;
  const int dir = bid >> 7, bg = (bid >> 4) & 7, t0 = (bid & 15) * 32;
  const int b0 = bg * 16;
  const int ss = tid >> 5, cc = tid & 31;
  const float* xf = (const float*)xin_;
  const u16* xh = (const u16*)xin_;

  if constexpr (BN) {
    for (int c = tid; c < 128; c += 512) {
      float s0 = stats[2 * c], s1 = stats[2 * c + 1];
      float m = s0 * (1.f / 65536.f);
      float v = s1 * (1.f / 65536.f) - m * m;
      float inv = rsqrtf(v + EPS_);
      float a = bng[c] * inv;
      sc[c] = a; sh[c] = bnb[c] - m * a;
    }
    __syncthreads();
  }

  const s16x8* wihv = (const s16x8*)wihP;
  s16x8 aw[NKS][4];
#pragma unroll
  for (int ks = 0; ks < NKS; ++ks)
#pragma unroll
    for (int g = 0; g < 4; ++g)
      aw[ks][g] = wihv[(((dir * NKS + ks) * 4 + g) * 8 + wv) * 64 + lane];

  f32x4 bias4[4];
#pragma unroll
  for (int g = 0; g < 4; ++g)
    bias4[g] = *(const f32x4*)&bias[dir * 512 + g * 128 + wv * 16 + q * 4];

  // stage t0
  if constexpr (KIN == 128) {
    f32x4 v = *(const f32x4*)&xf[((size_t)(b0 + ss) * 512 + t0) * 128 + cc * 4];
    s16x4 u;
#pragma unroll
    for (int j = 0; j < 4; ++j) {
      float xx = v[j];
      if constexpr (BN) xx = fmaxf(xx * sc[cc * 4 + j] + sh[cc * 4 + j], 0.f);
      u[j] = (short)f2bf(xx);
    }
    *(s16x4*)&xl[0][ss][cc * 4] = u;
  } else {
    *(s16x8*)&xl[0][ss][cc * 8] =
        *(const s16x8*)&xh[((size_t)(b0 + ss) * 512 + t0) * 256 + cc * 8];
  }
  __syncthreads();

  int cur = 0;
  for (int i = 0; i < 32; ++i) {
    const int t = t0 + i;
    const int tn = t0 + ((i < 31) ? i + 1 : 31);
    f32x4 xnf; s16x8 xnh;
    if constexpr (KIN == 128)
      xnf = *(const f32x4*)&xf[((size_t)(b0 + ss) * 512 + tn) * 128 + cc * 4];
    else
      xnh = *(const s16x8*)&xh[((size_t)(b0 + ss) * 512 + tn) * 256 + cc * 8];

    s16x8 bx[NKS];
#pragma unroll
    for (int ks = 0; ks < NKS; ++ks)
      bx[ks] = *(const s16x8*)&xl[cur][col][ks * 32 + q * 8];

    f32x4 a0 = bias4[0], a1 = bias4[1], a2 = bias4[2], a3 = bias4[3];
#pragma unroll
    for (int ks = 0; ks < NKS; ++ks) {
      a0 = mfma16(aw[ks][0], bx[ks], a0);
      a1 = mfma16(aw[ks][1], bx[ks], a1);
      a2 = mfma16(aw[ks][2], bx[ks], a2);
      a3 = mfma16(aw[ks][3], bx[ks], a3);
    }

    u16* op = xgo + (((size_t)((dir * 8 + bg) * 512 + t)) * 32 + wv * 4) * 256
            + (size_t)lane * 4;
#define STORE_G(G, A)                                              \
    { s16x4 o;                                                     \
      o[0] = (short)f2bf(A[0]); o[1] = (short)f2bf(A[1]);          \
      o[2] = (short)f2bf(A[2]); o[3] = (short)f2bf(A[3]);          \
      *(s16x4*)(op + G * 256) = o; }
    STORE_G(0, a0) STORE_G(1, a1) STORE_G(2, a2) STORE_G(3, a3)
#undef STORE_G

    // write prefetch into other buffer (no conflict with this step's reads)
    if constexpr (KIN == 128) {
      s16x4 u;
#pragma unroll
      for (int j = 0; j < 4; ++j) {
        float xx = xnf[j];
        if constexpr (BN) xx = fmaxf(xx * sc[cc * 4 + j] + sh[cc * 4 + j], 0.f);
        u[j] = (short)f2bf(xx);
      }
      *(s16x4*)&xl[cur ^ 1][ss][cc * 4] = u;
    } else {
      *(s16x8*)&xl[cur ^ 1][ss][cc * 8] = xnh;
    }
    __syncthreads();
    cur ^= 1;
  }
}

// ---------------- slim recurrent LSTM: gates = xg[t] + whh·h[t-1] ------------
// grid 16 = (dir, 16-sample group); 8 waves; whh resident (64 VGPR);
// hl double-buffered -> ONE raw barrier per step (lgkmcnt only, no vmcnt drain)
__global__ __launch_bounds__(512, 1) void lstm_kernel(
    const u16* __restrict__ whhP, const u16* __restrict__ xg,
    u16* __restrict__ hout) {
  __shared__ u16 hl[2][16][136];
  const int tid = threadIdx.x;
  const int wv = tid >> 6, lane = tid & 63, q = lane >> 4, col = lane & 15;
  const int dir = blockIdx.x >> 3, bg = blockIdx.x & 7, b0 = bg * 16;

  for (int n = tid; n < 16 * 136; n += 512) (&hl[0][0][0])[n] = 0;

  const s16x8* whhv = (const s16x8*)whhP;
  s16x8 awhh[4][4];
#pragma unroll
  for (int ks = 0; ks < 4; ++ks)
#pragma unroll
    for (int g = 0; g < 4; ++g)
      awhh[ks][g] = whhv[(((dir * 4 + ks) * 4 + g) * 8 + wv) * 64 + lane];

  // xg per-thread base; addr(t,g) = base + t*8192 + g*256 (elements)
  const u16* xgp = xg + ((size_t)(dir * 8 + bg)) * 512 * 8192
                 + (size_t)(wv * 4) * 256 + (size_t)lane * 4;

  const int tstep = dir ? -1 : 1;
  int t = dir ? 511 : 0;

  s16x4 xn0 = *(const s16x4*)(xgp + (size_t)t * 8192);
  s16x4 xn1 = *(const s16x4*)(xgp + (size_t)t * 8192 + 256);
  s16x4 xn2 = *(const s16x4*)(xgp + (size_t)t * 8192 + 512);
  s16x4 xn3 = *(const s16x4*)(xgp + (size_t)t * 8192 + 768);

  __syncthreads();   // hl zeros visible

  float c0 = 0.f, c1 = 0.f, c2 = 0.f, c3 = 0.f;
  int cur = 0;

  for (int it = 0; it < 512; ++it) {
    s16x4 xc0 = xn0, xc1 = xn1, xc2 = xn2, xc3 = xn3;
    const int tn = (it < 511) ? t + tstep : t;
    xn0 = *(const s16x4*)(xgp + (size_t)tn * 8192);
    xn1 = *(const s16x4*)(xgp + (size_t)tn * 8192 + 256);
    xn2 = *(const s16x4*)(xgp + (size_t)tn * 8192 + 512);
    xn3 = *(const s16x4*)(xgp + (size_t)tn * 8192 + 768);

    s16x8 bh[4];
#pragma unroll
    for (int ks = 0; ks < 4; ++ks)
      bh[ks] = *(const s16x8*)&hl[cur][col][ks * 32 + q * 8];

    f32x4 a0, a1, a2, a3;
#pragma unroll
    for (int e = 0; e < 4; ++e) {
      a0[e] = bf2f((u16)xc0[e]); a1[e] = bf2f((u16)xc1[e]);
      a2[e] = bf2f((u16)xc2[e]); a3[e] = bf2f((u16)xc3[e]);
    }
#pragma unroll
    for (int ks = 0; ks < 4; ++ks) {
      a0 = mfma16(awhh[ks][0], bh[ks], a0);
      a1 = mfma16(awhh[ks][1], bh[ks], a1);
      a2 = mfma16(awhh[ks][2], bh[ks], a2);
      a3 = mfma16(awhh[ks][3], bh[ks], a3);
    }

    f32x4 hn;
#define GATE_STEP(E, CP)                                            \
    {                                                               \
      float sI = sigf(a0[E]); float sF = sigf(a1[E]);               \
      float tG = tanhf_(a2[E]); float sO = sigf(a3[E]);             \
      float cn = sF * CP + sI * tG;                                 \
      CP = cn;                                                      \
      hn[E] = sO * tanhf_(cn);                                      \
    }
    GATE_STEP(0, c0) GATE_STEP(1, c1) GATE_STEP(2, c2) GATE_STEP(3, c3)
#undef GATE_STEP

    s16x4 hb;
#pragma unroll
    for (int e = 0; e < 4; ++e) hb[e] = (short)f2bf(hn[e]);
    *(s16x4*)&hout[((size_t)(b0 + col) * 512 + t) * 256 + dir * 128 + wv * 16 + q * 4] = hb;
    *(s16x4*)&hl[cur ^ 1][col][wv * 16 + q * 4] = hb;

    // barrier with LDS-only drain: stores & xg prefetches stay in flight
    asm volatile("s_waitcnt lgkmcnt(0)" ::: "memory");
    __builtin_amdgcn_sched_barrier(0);
    __builtin_amdgcn_s_barrier();
    __builtin_amdgcn_sched_barrier(0);

    cur ^= 1;
    t += tstep;
  }
}

// ---------------- attention pooling: scores -> softmax -> attended -----------
__global__ __launch_bounds__(256) void attn_kernel(
    const u16* __restrict__ h1, const float* __restrict__ attw,
    const float* __restrict__ attb, float* __restrict__ out_attn,
    float* __restrict__ attended) {
  const int b = blockIdx.x;
  const int tid = threadIdx.x;
  const int w = tid >> 6, l = tid & 63;
  __shared__ float sl[512];
  __shared__ float red[256];
  __shared__ float red2[4][256];

  // scores: wave w handles t = w*128+i; lanes cover 256 ch (coalesced)
  f32x4 wv4 = *(const f32x4*)&attw[l * 4];
  const float ab = attb[0];
  for (int i = 0; i < 128; ++i) {
    int t = w * 128 + i;
    s16x4 v = *(const s16x4*)&h1[((size_t)b * 512 + t) * 256 + l * 4];
    float s = bf2f((u16)v[0]) * wv4[0] + bf2f((u16)v[1]) * wv4[1]
            + bf2f((u16)v[2]) * wv4[2] + bf2f((u16)v[3]) * wv4[3];
#pragma unroll
    for (int m = 32; m > 0; m >>= 1) s += __shfl_xor(s, m, 64);
    if (l == 0) sl[t] = s + ab;
  }
  __syncthreads();

  red[tid] = fmaxf(sl[tid], sl[tid + 256]);
  __syncthreads();
  for (int st = 128; st > 0; st >>= 1) {
    if (tid < st) red[tid] = fmaxf(red[tid], red[tid + st]);
    __syncthreads();
  }
  const float mx = red[0];
  __syncthreads();

  float e0 = __expf(sl[tid] - mx);
  float e1 = __expf(sl[tid + 256] - mx);
  sl[tid] = e0; sl[tid + 256] = e1;
  red[tid] = e0 + e1;
  __syncthreads();
  for (int st = 128; st > 0; st >>= 1) {
    if (tid < st) red[tid] += red[tid + st];
    __syncthreads();
  }
  const float inv = 1.f / red[0];

  out_attn[(size_t)b * 512 + tid] = sl[tid] * inv;
  out_attn[(size_t)b * 512 + tid + 256] = sl[tid + 256] * inv;
  __syncthreads();

  // attended: wave w covers its 128 t's, lanes cover ch (coalesced); LDS reduce
  float a0 = 0.f, a1 = 0.f, a2 = 0.f, a3 = 0.f;
  for (int i = 0; i < 128; ++i) {
    int t = w * 128 + i;
    float p = sl[t] * inv;
    s16x4 v = *(const s16x4*)&h1[((size_t)b * 512 + t) * 256 + l * 4];
    a0 += p * bf2f((u16)v[0]); a1 += p * bf2f((u16)v[1]);
    a2 += p * bf2f((u16)v[2]); a3 += p * bf2f((u16)v[3]);
  }
  red2[w][l * 4 + 0] = a0; red2[w][l * 4 + 1] = a1;
  red2[w][l * 4 + 2] = a2; red2[w][l * 4 + 3] = a3;
  __syncthreads();
  attended[b * 256 + tid] =
      red2[0][tid] + red2[1][tid] + red2[2][tid] + red2[3][tid];
}

// ---------------- group-routed decoder MLP (selected expert only) ------------
__global__ __launch_bounds__(64) void dec_kernel(
    const float* __restrict__ attended, const int* __restrict__ labels,
    const float* __restrict__ w1, const float* __restrict__ b1,
    const float* __restrict__ w2, const float* __restrict__ b2,
    const float* __restrict__ w3, const float* __restrict__ b3,
    float* __restrict__ preds) {
  const int b = blockIdx.x;
  const int tid = threadIdx.x;
  const int g = labels[b];
  __shared__ float al[256];
  __shared__ float hl1[64];
  __shared__ float hl2[32];

  for (int i = tid; i < 256; i += 64) al[i] = attended[b * 256 + i];
  __syncthreads();

  {
    const float* wr = &w1[(size_t)(g * 64 + tid) * 256];
    float a = b1[g * 64 + tid];
    for (int d = 0; d < 256; d += 4) {
      f32x4 wv = *(const f32x4*)&wr[d];
      a += al[d] * wv[0] + al[d + 1] * wv[1] + al[d + 2] * wv[2] + al[d + 3] * wv[3];
    }
    hl1[tid] = fmaxf(a, 0.f);
  }
  __syncthreads();
  if (tid < 32) {
    const float* wr = &w2[(size_t)(g * 32 + tid) * 64];
    float a = b2[g * 32 + tid];
    for (int d = 0; d < 64; d += 4) {
      f32x4 wv = *(const f32x4*)&wr[d];
      a += hl1[d] * wv[0] + hl1[d + 1] * wv[1] + hl1[d + 2] * wv[2] + hl1[d + 3] * wv[3];
    }
    hl2[tid] = fmaxf(a, 0.f);
  }
  __syncthreads();
  if (tid < 32) {
    float a = hl2[tid] * w3[g * 32 + tid];
#pragma unroll
    for (int m = 16; m > 0; m >>= 1) a += __shfl_xor(a, m, 32);
    if (tid == 0) preds[b] = a + b3[g];
  }
}

// ---------------- host-side pipeline ----------------------------------------
extern "C" void kernel_launch(void* const* d_in, const int* in_sizes, int n_in,
                              void* d_out, int out_size, void* d_ws, size_t ws_size,
                              hipStream_t stream) {
  const float* x      = (const float*)d_in[0];
  const int*   labels = (const int*)d_in[1];
  const float* conv1w = (const float*)d_in[2];
  const float* conv1b = (const float*)d_in[3];
  const float* bn1g   = (const float*)d_in[4];
  const float* bn1b   = (const float*)d_in[5];
  const float* conv2w = (const float*)d_in[6];
  const float* conv2b = (const float*)d_in[7];
  const float* bn2g   = (const float*)d_in[8];
  const float* bn2b   = (const float*)d_in[9];
  const float* wih0   = (const float*)d_in[10];
  const float* whh0   = (const float*)d_in[11];
  const float* b0     = (const float*)d_in[12];
  const float* wih1   = (const float*)d_in[13];
  const float* whh1   = (const float*)d_in[14];
  const float* b1     = (const float*)d_in[15];
  const float* attw   = (const float*)d_in[16];
  const float* attb   = (const float*)d_in[17];
  const float* dw1    = (const float*)d_in[18];
  const float* db1    = (const float*)d_in[19];
  const float* dw2    = (const float*)d_in[20];
  const float* db2    = (const float*)d_in[21];
  const float* dw3    = (const float*)d_in[22];
  const float* db3    = (const float*)d_in[23];

  char* ws = (char*)d_ws;
  u16*   whh0P = (u16*)  (ws + 0x000000);   // 256KB A-frag bf16
  u16*   whh1P = (u16*)  (ws + 0x040000);   // 256KB
  u16*   wih0P = (u16*)  (ws + 0x080000);   // 256KB
  u16*   wih1P = (u16*)  (ws + 0x0C0000);   // 512KB
  float* wt1   = (float*)(ws + 0x140000);   // 96KB  conv1 w transposed
  float* wt2   = (float*)(ws + 0x158000);   // 96KB
  float* st1   = (float*)(ws + 0x170000);   // 512B  {sum,sumsq} x64
  float* st2   = (float*)(ws + 0x170200);   // 1KB   x128
  float* attd  = (float*)(ws + 0x170600);   // 128KB attended (B,256)
  u16*   h0    = (u16*)  (ws + 0x200000);   // 33.5MB bf16 (B,T,256)
  float* y2    = (float*)(ws + 0x2200000);  // 33.5MB f32 (B,T,128)
  u16*   h1    = (u16*)  (ws + 0x2200000);  // overlays y2 (dead after xg L1)
  u16*   xgb   = (u16*)  (ws + 0x4200000);  // 134.2MB bf16 xg (reused L1/L2)
  float* y1    = (float*)(ws + 0x4200000);  // 16MB, overlays xg (dead before)

  float* preds    = (float*)d_out;          // (B,1)
  float* attn_out = (float*)d_out + 128;    // (B,T)

  hipMemsetAsync(ws + 0x170000, 0, 0x600, stream);  // zero stats

  convw_kernel<<<512, 256, 0, stream>>>(wih0, wih0P, 128, 2, 131072);
  convw_kernel<<<512, 256, 0, stream>>>(whh0, whh0P, 128, 2, 131072);
  convw_kernel<<<1024, 256, 0, stream>>>(wih1, wih1P, 256, 3, 262144);
  convw_kernel<<<512, 256, 0, stream>>>(whh1, whh1P, 128, 2, 131072);
  transw_kernel<<<96, 256, 0, stream>>>(conv1w, wt1, 128, 64, 24576);
  transw_kernel<<<96, 256, 0, stream>>>(conv2w, wt2, 64, 128, 24576);

  conv_kernel<128, 64, false><<<1024, 256, 0, stream>>>(
      x, wt1, conv1b, nullptr, nullptr, nullptr, y1, st1);
  conv_kernel<64, 128, true><<<1024, 256, 0, stream>>>(
      y1, wt2, conv2b, st1, bn1g, bn1b, y2, st2);

  xg_kernel<128, true><<<256, 512, 0, stream>>>(
      y2, st2, bn2g, bn2b, wih0P, b0, xgb);
  lstm_kernel<<<16, 512, 0, stream>>>(whh0P, xgb, h0);
  xg_kernel<256, false><<<256, 512, 0, stream>>>(
      h0, nullptr, nullptr, nullptr, wih1P, b1, xgb);
  lstm_kernel<<<16, 512, 0, stream>>>(whh1P, xgb, h1);

  attn_kernel<<<128, 256, 0, stream>>>(h1, attw, attb, attn_out, attd);
  dec_kernel<<<128, 64, 0, stream>>>(attd, labels, dw1, db1, dw2, db2, dw3, db3, preds);
}

// Round 8
// 1752.414 us; speedup vs baseline: 1.3713x; 1.2103x over previous
//
#include <hip/hip_runtime.h>
#include <hip/hip_bf16.h>

// B=128, T=512, F_IN=128, H=128
#define EPS_ 1e-5f

typedef __attribute__((ext_vector_type(4))) float f32x4;
typedef __attribute__((ext_vector_type(8))) short s16x8;
typedef __attribute__((ext_vector_type(4))) short s16x4;
typedef unsigned short u16;

static __device__ __forceinline__ u16 f2bf(float f) {
  __hip_bfloat16 h = __float2bfloat16(f);
  return *reinterpret_cast<u16*>(&h);
}
static __device__ __forceinline__ float bf2f(u16 u) {
  union { float f; unsigned int i; } v; v.i = ((unsigned int)u) << 16; return v.f;
}
static __device__ __forceinline__ float sigf(float x) {
  return __builtin_amdgcn_rcpf(1.f + __expf(-x));
}
static __device__ __forceinline__ float tanhf_(float x) {
  return 2.f * __builtin_amdgcn_rcpf(1.f + __expf(-2.f * x)) - 1.f;
}
static __device__ __forceinline__ f32x4 mfma16(s16x8 a, s16x8 b, f32x4 c) {
  return __builtin_amdgcn_mfma_f32_16x16x32_bf16(a, b, c, 0, 0, 0);
}

// ---------------- LSTM weight pre-permute: (d,4H,K) f32 -> A-frag bf16 -------
// dst linear: ((((d*NKS+ks)*4+g)*8+w)*64+lane)*8+e ; r=g*128+w*16+(lane&15),
// k=ks*32+(lane>>4)*8+e  (A-frag mapping of mfma_f32_16x16x32_bf16)
__global__ void convw_kernel(const float* __restrict__ src, u16* __restrict__ dst,
                             int KIN, int ksbits, int total) {
  int i = blockIdx.x * 256 + threadIdx.x;
  if (i >= total) return;
  int e = i & 7;
  int lane = (i >> 3) & 63;
  int w = (i >> 9) & 7;
  int g = (i >> 12) & 3;
  int t2 = i >> 14;
  int ks = t2 & ((1 << ksbits) - 1);
  int d = t2 >> ksbits;
  int r = g * 128 + w * 16 + (lane & 15);
  int k = ks * 32 + (lane >> 4) * 8 + e;
  dst[i] = f2bf(src[((size_t)d * 512 + r) * KIN + k]);
}

// ---------------- conv weight pre-permute: (O,I,3) f32 -> A-frag bf16 --------
// dst linear: ((ks*NW + wb)*64 + lane)*8 + e ; oc = wb*16+(lane&15),
// k = ks*32+(lane>>4)*8+e, tap = k/IC, ic = k%IC
__global__ void convwf_kernel(const float* __restrict__ src, u16* __restrict__ dst,
                              int IC, int NW, int total) {
  int i = blockIdx.x * 256 + threadIdx.x;
  if (i >= total) return;
  int e = i & 7;
  int lane = (i >> 3) & 63;
  int blk = i >> 9;
  int wb = blk % NW;
  int ks = blk / NW;
  int oc = wb * 16 + (lane & 15);
  int k = ks * 32 + (lane >> 4) * 8 + e;
  int tap = k / IC;
  int ic = k - tap * IC;
  dst[i] = f2bf(src[(oc * IC + ic) * 3 + tap]);
}

// ---------------- conv1d (k=3,pad=1) as MFMA GEMM + batch-stat atomics -------
// M=OC (A-frags resident), N=(b,t), K=3*IC. Block: 512 thr, 64 t's of one b.
// x staged in LDS bf16 with halo + XOR swizzle ((r&7)<<4); BN+ReLU on stage.
template<int IC, int NW, bool BN>
__global__ __launch_bounds__(512, 1) void convm_kernel(
    const float* __restrict__ xin, const u16* __restrict__ wP,
    const float* __restrict__ bsrc, const float* __restrict__ stats_in,
    const float* __restrict__ g_in, const float* __restrict__ beta_in,
    float* __restrict__ yout, float* __restrict__ stats_out) {
  constexpr int OC = NW * 16;
  constexpr int NKS = (3 * IC) / 32;           // 12 (conv1) or 6 (conv2)
  constexpr int ICQ = IC / 32;                 // k-octets per tap row: 4 or 2
  __shared__ u16 xs[66 * IC];
  __shared__ float insc[IC], insh[IC];

  const int tid = threadIdx.x;
  const int wv = tid >> 6, lane = tid & 63, q = lane >> 4, col = lane & 15;
  const int b = blockIdx.x >> 3;
  const int t0 = (blockIdx.x & 7) * 64;
  char* xsb = (char*)xs;

  if constexpr (BN) {
    for (int c = tid; c < IC; c += 512) {
      float s0 = stats_in[2 * c], s1 = stats_in[2 * c + 1];
      float m = s0 * (1.f / 65536.f);
      float v = s1 * (1.f / 65536.f) - m * m;
      float inv = rsqrtf(v + EPS_);
      float a = g_in[c] * inv;
      insc[c] = a; insh[c] = beta_in[c] - m * a;
    }
    __syncthreads();
  }

  // stage x rows t0-1 .. t0+64 (66 rows) as bf16, swizzled
  for (int n = tid; n < 66 * (IC / 4); n += 512) {
    int r = n / (IC / 4);
    int c4 = (n % (IC / 4)) * 4;
    int t = t0 + r - 1;
    float v0 = 0.f, v1 = 0.f, v2 = 0.f, v3 = 0.f;
    if (t >= 0 && t < 512) {
      f32x4 v = *(const f32x4*)&xin[((size_t)b * 512 + t) * IC + c4];
      v0 = v[0]; v1 = v[1]; v2 = v[2]; v3 = v[3];
      if constexpr (BN) {   // pad rows stay 0 (zero AFTER bn+relu semantics)
        v0 = fmaxf(v0 * insc[c4 + 0] + insh[c4 + 0], 0.f);
        v1 = fmaxf(v1 * insc[c4 + 1] + insh[c4 + 1], 0.f);
        v2 = fmaxf(v2 * insc[c4 + 2] + insh[c4 + 2], 0.f);
        v3 = fmaxf(v3 * insc[c4 + 3] + insh[c4 + 3], 0.f);
      }
    }
    s16x4 u;
    u[0] = (short)f2bf(v0); u[1] = (short)f2bf(v1);
    u[2] = (short)f2bf(v2); u[3] = (short)f2bf(v3);
    int byte = ((r * IC + c4) * 2) ^ ((r & 7) << 4);
    *(s16x4*)(xsb + byte) = u;
  }
  __syncthreads();

  // resident A-frags (weights) for this wave's oc block
  const int wb = (NW == 8) ? wv : (wv & 3);
  const s16x8* wPv = (const s16x8*)wP;
  s16x8 aA[NKS];
#pragma unroll
  for (int ks = 0; ks < NKS; ++ks)
    aA[ks] = wPv[(ks * NW + wb) * 64 + lane];

  f32x4 bias4 = *(const f32x4*)&bsrc[wb * 16 + q * 4];

  constexpr int NSUB = (NW == 8) ? 4 : 2;      // subtiles per wave
  const int st0 = (NW == 8) ? 0 : ((wv >> 2) * 2);

  float ssum0 = 0.f, ssum1 = 0.f, ssum2 = 0.f, ssum3 = 0.f;
  float ssq0 = 0.f, ssq1 = 0.f, ssq2 = 0.f, ssq3 = 0.f;

#pragma unroll
  for (int s = 0; s < NSUB; ++s) {
    const int tbase = (st0 + s) * 16;
    const int t_loc = tbase + col;
    f32x4 acc = bias4;
#pragma unroll
    for (int ks = 0; ks < NKS; ++ks) {
      const int tap = ks / ICQ;
      const int icb = (ks % ICQ) * 32 + q * 8;
      const int R = t_loc + tap;
      int byte = ((R * IC + icb) * 2) ^ ((R & 7) << 4);
      s16x8 bB = *(const s16x8*)(xsb + byte);
      acc = mfma16(aA[ks], bB, acc);
    }
    *(f32x4*)&yout[((size_t)b * 512 + t0 + t_loc) * OC + wb * 16 + q * 4] = acc;
    ssum0 += acc[0]; ssq0 += acc[0] * acc[0];
    ssum1 += acc[1]; ssq1 += acc[1] * acc[1];
    ssum2 += acc[2]; ssq2 += acc[2] * acc[2];
    ssum3 += acc[3]; ssq3 += acc[3] * acc[3];
  }

  // reduce over the 16 cols (t) of this wave, one atomic pair per oc
#define RED16(S)                                   \
  S += __shfl_xor(S, 1, 64); S += __shfl_xor(S, 2, 64); \
  S += __shfl_xor(S, 4, 64); S += __shfl_xor(S, 8, 64);
  RED16(ssum0) RED16(ssum1) RED16(ssum2) RED16(ssum3)
  RED16(ssq0)  RED16(ssq1)  RED16(ssq2)  RED16(ssq3)
#undef RED16
  if (col == 0) {
    const int ocb = wb * 16 + q * 4;
    atomicAdd(&stats_out[2 * (ocb + 0)], ssum0);
    atomicAdd(&stats_out[2 * (ocb + 0) + 1], ssq0);
    atomicAdd(&stats_out[2 * (ocb + 1)], ssum1);
    atomicAdd(&stats_out[2 * (ocb + 1) + 1], ssq1);
    atomicAdd(&stats_out[2 * (ocb + 2)], ssum2);
    atomicAdd(&stats_out[2 * (ocb + 2) + 1], ssq2);
    atomicAdd(&stats_out[2 * (ocb + 3)], ssum3);
    atomicAdd(&stats_out[2 * (ocb + 3) + 1], ssq3);
  }
}

// ---------------- xg = wih·x + b, batched over all (dir,b,t) -----------------
// Output layout = LSTM D-frag order: elem((((dir*8+bg)*512+t)*8+wv)*4+g)*256
// + lane*4 + e, bf16. 256 blocks of 512 thr; aw resident per wave.
template<int KIN, bool BN>
__global__ __launch_bounds__(512, 1) void xg_kernel(
    const void* __restrict__ xin_, const float* __restrict__ stats,
    const float* __restrict__ bng, const float* __restrict__ bnb,
    const u16* __restrict__ wihP, const float* __restrict__ bias,
    u16* __restrict__ xgo) {
  constexpr int NKS = KIN / 32;
  constexpr int XSTR = KIN + 8;
  __shared__ u16 xl[2][16][XSTR];
  __shared__ float sc[128], sh[128];

  const int tid = threadIdx.x;
  const int wv = tid >> 6, lane = tid & 63, q = lane >> 4, col = lane & 15;
  const int bid = blockIdx.x;
  const int dir = bid >> 7, bg = (bid >> 4) & 7, t0 = (bid & 15) * 32;
  const int b0 = bg * 16;
  const int ss = tid >> 5, cc = tid & 31;
  const float* xf = (const float*)xin_;
  const u16* xh = (const u16*)xin_;

  if constexpr (BN) {
    for (int c = tid; c < 128; c += 512) {
      float s0 = stats[2 * c], s1 = stats[2 * c + 1];
      float m = s0 * (1.f / 65536.f);
      float v = s1 * (1.f / 65536.f) - m * m;
      float inv = rsqrtf(v + EPS_);
      float a = bng[c] * inv;
      sc[c] = a; sh[c] = bnb[c] - m * a;
    }
    __syncthreads();
  }

  const s16x8* wihv = (const s16x8*)wihP;
  s16x8 aw[NKS][4];
#pragma unroll
  for (int ks = 0; ks < NKS; ++ks)
#pragma unroll
    for (int g = 0; g < 4; ++g)
      aw[ks][g] = wihv[(((dir * NKS + ks) * 4 + g) * 8 + wv) * 64 + lane];

  f32x4 bias4[4];
#pragma unroll
  for (int g = 0; g < 4; ++g)
    bias4[g] = *(const f32x4*)&bias[dir * 512 + g * 128 + wv * 16 + q * 4];

  // stage t0
  if constexpr (KIN == 128) {
    f32x4 v = *(const f32x4*)&xf[((size_t)(b0 + ss) * 512 + t0) * 128 + cc * 4];
    s16x4 u;
#pragma unroll
    for (int j = 0; j < 4; ++j) {
      float xx = v[j];
      if constexpr (BN) xx = fmaxf(xx * sc[cc * 4 + j] + sh[cc * 4 + j], 0.f);
      u[j] = (short)f2bf(xx);
    }
    *(s16x4*)&xl[0][ss][cc * 4] = u;
  } else {
    *(s16x8*)&xl[0][ss][cc * 8] =
        *(const s16x8*)&xh[((size_t)(b0 + ss) * 512 + t0) * 256 + cc * 8];
  }
  __syncthreads();

  int cur = 0;
  for (int i = 0; i < 32; ++i) {
    const int t = t0 + i;
    const int tn = t0 + ((i < 31) ? i + 1 : 31);
    f32x4 xnf; s16x8 xnh;
    if constexpr (KIN == 128)
      xnf = *(const f32x4*)&xf[((size_t)(b0 + ss) * 512 + tn) * 128 + cc * 4];
    else
      xnh = *(const s16x8*)&xh[((size_t)(b0 + ss) * 512 + tn) * 256 + cc * 8];

    s16x8 bx[NKS];
#pragma unroll
    for (int ks = 0; ks < NKS; ++ks)
      bx[ks] = *(const s16x8*)&xl[cur][col][ks * 32 + q * 8];

    f32x4 a0 = bias4[0], a1 = bias4[1], a2 = bias4[2], a3 = bias4[3];
#pragma unroll
    for (int ks = 0; ks < NKS; ++ks) {
      a0 = mfma16(aw[ks][0], bx[ks], a0);
      a1 = mfma16(aw[ks][1], bx[ks], a1);
      a2 = mfma16(aw[ks][2], bx[ks], a2);
      a3 = mfma16(aw[ks][3], bx[ks], a3);
    }

    u16* op = xgo + (((size_t)((dir * 8 + bg) * 512 + t)) * 32 + wv * 4) * 256
            + (size_t)lane * 4;
#define STORE_G(G, A)                                              \
    { s16x4 o;                                                     \
      o[0] = (short)f2bf(A[0]); o[1] = (short)f2bf(A[1]);          \
      o[2] = (short)f2bf(A[2]); o[3] = (short)f2bf(A[3]);          \
      *(s16x4*)(op + G * 256) = o; }
    STORE_G(0, a0) STORE_G(1, a1) STORE_G(2, a2) STORE_G(3, a3)
#undef STORE_G

    if constexpr (KIN == 128) {
      s16x4 u;
#pragma unroll
      for (int j = 0; j < 4; ++j) {
        float xx = xnf[j];
        if constexpr (BN) xx = fmaxf(xx * sc[cc * 4 + j] + sh[cc * 4 + j], 0.f);
        u[j] = (short)f2bf(xx);
      }
      *(s16x4*)&xl[cur ^ 1][ss][cc * 4] = u;
    } else {
      *(s16x8*)&xl[cur ^ 1][ss][cc * 8] = xnh;
    }
    __syncthreads();
    cur ^= 1;
  }
}

// ---------------- slim recurrent LSTM: gates = xg[t] + whh·h[t-1] ------------
__global__ __launch_bounds__(512, 1) void lstm_kernel(
    const u16* __restrict__ whhP, const u16* __restrict__ xg,
    u16* __restrict__ hout) {
  __shared__ u16 hl[2][16][136];
  const int tid = threadIdx.x;
  const int wv = tid >> 6, lane = tid & 63, q = lane >> 4, col = lane & 15;
  const int dir = blockIdx.x >> 3, bg = blockIdx.x & 7, b0 = bg * 16;

  for (int n = tid; n < 16 * 136; n += 512) (&hl[0][0][0])[n] = 0;

  const s16x8* whhv = (const s16x8*)whhP;
  s16x8 awhh[4][4];
#pragma unroll
  for (int ks = 0; ks < 4; ++ks)
#pragma unroll
    for (int g = 0; g < 4; ++g)
      awhh[ks][g] = whhv[(((dir * 4 + ks) * 4 + g) * 8 + wv) * 64 + lane];

  const u16* xgp = xg + ((size_t)(dir * 8 + bg)) * 512 * 8192
                 + (size_t)(wv * 4) * 256 + (size_t)lane * 4;

  const int tstep = dir ? -1 : 1;
  int t = dir ? 511 : 0;

  s16x4 xn0 = *(const s16x4*)(xgp + (size_t)t * 8192);
  s16x4 xn1 = *(const s16x4*)(xgp + (size_t)t * 8192 + 256);
  s16x4 xn2 = *(const s16x4*)(xgp + (size_t)t * 8192 + 512);
  s16x4 xn3 = *(const s16x4*)(xgp + (size_t)t * 8192 + 768);

  __syncthreads();   // hl zeros visible

  float c0 = 0.f, c1 = 0.f, c2 = 0.f, c3 = 0.f;
  int cur = 0;

  for (int it = 0; it < 512; ++it) {
    s16x4 xc0 = xn0, xc1 = xn1, xc2 = xn2, xc3 = xn3;
    const int tn = (it < 511) ? t + tstep : t;
    xn0 = *(const s16x4*)(xgp + (size_t)tn * 8192);
    xn1 = *(const s16x4*)(xgp + (size_t)tn * 8192 + 256);
    xn2 = *(const s16x4*)(xgp + (size_t)tn * 8192 + 512);
    xn3 = *(const s16x4*)(xgp + (size_t)tn * 8192 + 768);

    s16x8 bh[4];
#pragma unroll
    for (int ks = 0; ks < 4; ++ks)
      bh[ks] = *(const s16x8*)&hl[cur][col][ks * 32 + q * 8];

    f32x4 a0, a1, a2, a3;
#pragma unroll
    for (int e = 0; e < 4; ++e) {
      a0[e] = bf2f((u16)xc0[e]); a1[e] = bf2f((u16)xc1[e]);
      a2[e] = bf2f((u16)xc2[e]); a3[e] = bf2f((u16)xc3[e]);
    }
#pragma unroll
    for (int ks = 0; ks < 4; ++ks) {
      a0 = mfma16(awhh[ks][0], bh[ks], a0);
      a1 = mfma16(awhh[ks][1], bh[ks], a1);
      a2 = mfma16(awhh[ks][2], bh[ks], a2);
      a3 = mfma16(awhh[ks][3], bh[ks], a3);
    }

    f32x4 hn;
#define GATE_STEP(E, CP)                                            \
    {                                                               \
      float sI = sigf(a0[E]); float sF = sigf(a1[E]);               \
      float tG = tanhf_(a2[E]); float sO = sigf(a3[E]);             \
      float cn = sF * CP + sI * tG;                                 \
      CP = cn;                                                      \
      hn[E] = sO * tanhf_(cn);                                      \
    }
    GATE_STEP(0, c0) GATE_STEP(1, c1) GATE_STEP(2, c2) GATE_STEP(3, c3)
#undef GATE_STEP

    s16x4 hb;
#pragma unroll
    for (int e = 0; e < 4; ++e) hb[e] = (short)f2bf(hn[e]);
    *(s16x4*)&hout[((size_t)(b0 + col) * 512 + t) * 256 + dir * 128 + wv * 16 + q * 4] = hb;
    *(s16x4*)&hl[cur ^ 1][col][wv * 16 + q * 4] = hb;

    // barrier with LDS-only drain: stores & xg prefetches stay in flight
    asm volatile("s_waitcnt lgkmcnt(0)" ::: "memory");
    __builtin_amdgcn_sched_barrier(0);
    __builtin_amdgcn_s_barrier();
    __builtin_amdgcn_sched_barrier(0);

    cur ^= 1;
    t += tstep;
  }
}

// ---------------- attention pooling: scores -> softmax -> attended -----------
__global__ __launch_bounds__(256) void attn_kernel(
    const u16* __restrict__ h1, const float* __restrict__ attw,
    const float* __restrict__ attb, float* __restrict__ out_attn,
    float* __restrict__ attended) {
  const int b = blockIdx.x;
  const int tid = threadIdx.x;
  const int w = tid >> 6, l = tid & 63;
  __shared__ float sl[512];
  __shared__ float red[256];
  __shared__ float red2[4][256];

  f32x4 wv4 = *(const f32x4*)&attw[l * 4];
  const float ab = attb[0];
  for (int i = 0; i < 128; ++i) {
    int t = w * 128 + i;
    s16x4 v = *(const s16x4*)&h1[((size_t)b * 512 + t) * 256 + l * 4];
    float s = bf2f((u16)v[0]) * wv4[0] + bf2f((u16)v[1]) * wv4[1]
            + bf2f((u16)v[2]) * wv4[2] + bf2f((u16)v[3]) * wv4[3];
#pragma unroll
    for (int m = 32; m > 0; m >>= 1) s += __shfl_xor(s, m, 64);
    if (l == 0) sl[t] = s + ab;
  }
  __syncthreads();

  red[tid] = fmaxf(sl[tid], sl[tid + 256]);
  __syncthreads();
  for (int st = 128; st > 0; st >>= 1) {
    if (tid < st) red[tid] = fmaxf(red[tid], red[tid + st]);
    __syncthreads();
  }
  const float mx = red[0];
  __syncthreads();

  float e0 = __expf(sl[tid] - mx);
  float e1 = __expf(sl[tid + 256] - mx);
  sl[tid] = e0; sl[tid + 256] = e1;
  red[tid] = e0 + e1;
  __syncthreads();
  for (int st = 128; st > 0; st >>= 1) {
    if (tid < st) red[tid] += red[tid + st];
    __syncthreads();
  }
  const float inv = 1.f / red[0];

  out_attn[(size_t)b * 512 + tid] = sl[tid] * inv;
  out_attn[(size_t)b * 512 + tid + 256] = sl[tid + 256] * inv;
  __syncthreads();

  float a0 = 0.f, a1 = 0.f, a2 = 0.f, a3 = 0.f;
  for (int i = 0; i < 128; ++i) {
    int t = w * 128 + i;
    float p = sl[t] * inv;
    s16x4 v = *(const s16x4*)&h1[((size_t)b * 512 + t) * 256 + l * 4];
    a0 += p * bf2f((u16)v[0]); a1 += p * bf2f((u16)v[1]);
    a2 += p * bf2f((u16)v[2]); a3 += p * bf2f((u16)v[3]);
  }
  red2[w][l * 4 + 0] = a0; red2[w][l * 4 + 1] = a1;
  red2[w][l * 4 + 2] = a2; red2[w][l * 4 + 3] = a3;
  __syncthreads();
  attended[b * 256 + tid] =
      red2[0][tid] + red2[1][tid] + red2[2][tid] + red2[3][tid];
}

// ---------------- group-routed decoder MLP (selected expert only) ------------
__global__ __launch_bounds__(64) void dec_kernel(
    const float* __restrict__ attended, const int* __restrict__ labels,
    const float* __restrict__ w1, const float* __restrict__ b1,
    const float* __restrict__ w2, const float* __restrict__ b2,
    const float* __restrict__ w3, const float* __restrict__ b3,
    float* __restrict__ preds) {
  const int b = blockIdx.x;
  const int tid = threadIdx.x;
  const int g = labels[b];
  __shared__ float al[256];
  __shared__ float hl1[64];
  __shared__ float hl2[32];

  for (int i = tid; i < 256; i += 64) al[i] = attended[b * 256 + i];
  __syncthreads();

  {
    const float* wr = &w1[(size_t)(g * 64 + tid) * 256];
    float a = b1[g * 64 + tid];
    for (int d = 0; d < 256; d += 4) {
      f32x4 wv = *(const f32x4*)&wr[d];
      a += al[d] * wv[0] + al[d + 1] * wv[1] + al[d + 2] * wv[2] + al[d + 3] * wv[3];
    }
    hl1[tid] = fmaxf(a, 0.f);
  }
  __syncthreads();
  if (tid < 32) {
    const float* wr = &w2[(size_t)(g * 32 + tid) * 64];
    float a = b2[g * 32 + tid];
    for (int d = 0; d < 64; d += 4) {
      f32x4 wv = *(const f32x4*)&wr[d];
      a += hl1[d] * wv[0] + hl1[d + 1] * wv[1] + hl1[d + 2] * wv[2] + hl1[d + 3] * wv[3];
    }
    hl2[tid] = fmaxf(a, 0.f);
  }
  __syncthreads();
  if (tid < 32) {
    float a = hl2[tid] * w3[g * 32 + tid];
#pragma unroll
    for (int m = 16; m > 0; m >>= 1) a += __shfl_xor(a, m, 32);
    if (tid == 0) preds[b] = a + b3[g];
  }
}

// ---------------- host-side pipeline ----------------------------------------
extern "C" void kernel_launch(void* const* d_in, const int* in_sizes, int n_in,
                              void* d_out, int out_size, void* d_ws, size_t ws_size,
                              hipStream_t stream) {
  const float* x      = (const float*)d_in[0];
  const int*   labels = (const int*)d_in[1];
  const float* conv1w = (const float*)d_in[2];
  const float* conv1b = (const float*)d_in[3];
  const float* bn1g   = (const float*)d_in[4];
  const float* bn1b   = (const float*)d_in[5];
  const float* conv2w = (const float*)d_in[6];
  const float* conv2b = (const float*)d_in[7];
  const float* bn2g   = (const float*)d_in[8];
  const float* bn2b   = (const float*)d_in[9];
  const float* wih0   = (const float*)d_in[10];
  const float* whh0   = (const float*)d_in[11];
  const float* b0     = (const float*)d_in[12];
  const float* wih1   = (const float*)d_in[13];
  const float* whh1   = (const float*)d_in[14];
  const float* b1     = (const float*)d_in[15];
  const float* attw   = (const float*)d_in[16];
  const float* attb   = (const float*)d_in[17];
  const float* dw1    = (const float*)d_in[18];
  const float* db1    = (const float*)d_in[19];
  const float* dw2    = (const float*)d_in[20];
  const float* db2    = (const float*)d_in[21];
  const float* dw3    = (const float*)d_in[22];
  const float* db3    = (const float*)d_in[23];

  char* ws = (char*)d_ws;
  u16*   whh0P = (u16*)  (ws + 0x000000);   // 256KB A-frag bf16
  u16*   whh1P = (u16*)  (ws + 0x040000);   // 256KB
  u16*   wih0P = (u16*)  (ws + 0x080000);   // 256KB
  u16*   wih1P = (u16*)  (ws + 0x0C0000);   // 512KB
  u16*   cw1P  = (u16*)  (ws + 0x140000);   // 48KB conv1 w A-frag
  u16*   cw2P  = (u16*)  (ws + 0x150000);   // 48KB conv2 w A-frag
  float* st1   = (float*)(ws + 0x170000);   // 512B {sum,sumsq} x64
  float* st2   = (float*)(ws + 0x170200);   // 1KB  x128
  float* attd  = (float*)(ws + 0x170600);   // 128KB attended (B,256)
  u16*   h0    = (u16*)  (ws + 0x200000);   // 33.5MB bf16 (B,T,256)
  float* y2    = (float*)(ws + 0x2200000);  // 33.5MB f32 (B,T,128)
  u16*   h1    = (u16*)  (ws + 0x2200000);  // overlays y2 (dead after xg L1)
  u16*   xgb   = (u16*)  (ws + 0x4200000);  // 134.2MB bf16 xg (reused L1/L2)
  float* y1    = (float*)(ws + 0x4200000);  // 16MB, overlays xg (dead before)

  float* preds    = (float*)d_out;          // (B,1)
  float* attn_out = (float*)d_out + 128;    // (B,T)

  hipMemsetAsync(ws + 0x170000, 0, 0x600, stream);  // zero stats

  convw_kernel<<<512, 256, 0, stream>>>(wih0, wih0P, 128, 2, 131072);
  convw_kernel<<<512, 256, 0, stream>>>(whh0, whh0P, 128, 2, 131072);
  convw_kernel<<<1024, 256, 0, stream>>>(wih1, wih1P, 256, 3, 262144);
  convw_kernel<<<512, 256, 0, stream>>>(whh1, whh1P, 128, 2, 131072);
  convwf_kernel<<<96, 256, 0, stream>>>(conv1w, cw1P, 128, 4, 24576);
  convwf_kernel<<<96, 256, 0, stream>>>(conv2w, cw2P, 64, 8, 24576);

  convm_kernel<128, 4, false><<<1024, 512, 0, stream>>>(
      x, cw1P, conv1b, nullptr, nullptr, nullptr, y1, st1);
  convm_kernel<64, 8, true><<<1024, 512, 0, stream>>>(
      y1, cw2P, conv2b, st1, bn1g, bn1b, y2, st2);

  xg_kernel<128, true><<<256, 512, 0, stream>>>(
      y2, st2, bn2g, bn2b, wih0P, b0, xgb);
  lstm_kernel<<<16, 512, 0, stream>>>(whh0P, xgb, h0);
  xg_kernel<256, false><<<256, 512, 0, stream>>>(
      h0, nullptr, nullptr, nullptr, wih1P, b1, xgb);
  lstm_kernel<<<16, 512, 0, stream>>>(whh1P, xgb, h1);

  attn_kernel<<<128, 256, 0, stream>>>(h1, attw, attb, attn_out, attd);
  dec_kernel<<<128, 64, 0, stream>>>(attd, labels, dw1, db1, dw2, db2, dw3, db3, preds);
}